// Round 3
// baseline (279.668 us; speedup 1.0000x reference)
//
#include <hip/hip_runtime.h>

#define N_L 100000
#define N_V 1000
#define D_IN 64
#define HCH 64
#define D_OUT 32
#define E_LL 1000000

#define SCAN_BLK 256
#define NB ((N_L + SCAN_BLK - 1) / SCAN_BLK)   // 391 blocks

typedef unsigned int uint32;
typedef unsigned short ushort16;

__device__ inline float bf2f(unsigned short u) {
    return __uint_as_float(((uint32)u) << 16);
}
__device__ inline unsigned short f2bf(float f) {   // round-to-nearest-even
    uint32 u = __float_as_uint(f);
    u = (u + 0x7fffu + ((u >> 16) & 1u)) >> 16;
    return (unsigned short)u;
}

// ---- deg_i[c] += 1 over all ll-edges (int atomics, 4B fabric each) ------
__global__ void deg_kernel(const int* __restrict__ col,
                           int* __restrict__ deg, int E) {
    int i = blockIdx.x * blockDim.x + threadIdx.x;
    int stride = gridDim.x * blockDim.x;
    for (; i < E; i += stride)
        atomicAdd(&deg[col[i]], 1);
}

// ---- dinv[i] = deg>0 ? rsqrt(deg) : 0 ------------------------------------
__global__ void dinv_kernel(const int* __restrict__ deg,
                            float* __restrict__ dinv, int n) {
    int i = blockIdx.x * blockDim.x + threadIdx.x;
    if (i < n) {
        int d = deg[i];
        dinv[i] = (d > 0) ? rsqrtf((float)d) : 0.0f;
    }
}

// ---- xb[r,:] = bf16(x[r,:] * dinv[r])  (streaming, float4 -> ushort4) ----
__global__ void xbconv_kernel(const float* __restrict__ x,
                              const float* __restrict__ dinv,
                              unsigned short* __restrict__ xb) {
    int n4 = N_L * D_IN / 4;
    int idx = blockIdx.x * blockDim.x + threadIdx.x;
    int stride = gridDim.x * blockDim.x;
    for (; idx < n4; idx += stride) {
        float4 v = ((const float4*)x)[idx];
        float d = dinv[idx >> 4];          // (idx*4)>>6
        ushort4 o;
        o.x = f2bf(v.x * d);
        o.y = f2bf(v.y * d);
        o.z = f2bf(v.z * d);
        o.w = f2bf(v.w * d);
        ((ushort4*)xb)[idx] = o;
    }
}

// ---- scan stage A: per-block sums ---------------------------------------
__global__ void blocksum_kernel(const int* __restrict__ deg,
                                int* __restrict__ bsum) {
    __shared__ int sh[SCAN_BLK];
    int i = blockIdx.x * SCAN_BLK + threadIdx.x;
    sh[threadIdx.x] = (i < N_L) ? deg[i] : 0;
    __syncthreads();
    for (int s = SCAN_BLK / 2; s > 0; s >>= 1) {
        if (threadIdx.x < s) sh[threadIdx.x] += sh[threadIdx.x + s];
        __syncthreads();
    }
    if (threadIdx.x == 0) bsum[blockIdx.x] = sh[0];
}

// ---- scan stage B: exclusive scan of block sums (single block) ----------
__global__ void scan_bsum_kernel(const int* __restrict__ bsum,
                                 int* __restrict__ boff) {
    __shared__ int sh[512];
    int v = (threadIdx.x < NB) ? bsum[threadIdx.x] : 0;
    sh[threadIdx.x] = v;
    __syncthreads();
    for (int ofs = 1; ofs < 512; ofs <<= 1) {
        int add = (threadIdx.x >= ofs) ? sh[threadIdx.x - ofs] : 0;
        __syncthreads();
        sh[threadIdx.x] += add;
        __syncthreads();
    }
    if (threadIdx.x < NB) boff[threadIdx.x] = sh[threadIdx.x] - v;  // exclusive
}

// ---- scan stage C: per-block exclusive scan + offset -> rowptr, cursor --
__global__ void block_scan_kernel(const int* __restrict__ deg,
                                  const int* __restrict__ boff,
                                  int* __restrict__ rowptr,
                                  int* __restrict__ cursor) {
    __shared__ int sh[SCAN_BLK];
    int i = blockIdx.x * SCAN_BLK + threadIdx.x;
    int v = (i < N_L) ? deg[i] : 0;
    sh[threadIdx.x] = v;
    __syncthreads();
    for (int ofs = 1; ofs < SCAN_BLK; ofs <<= 1) {
        int add = (threadIdx.x >= ofs) ? sh[threadIdx.x - ofs] : 0;
        __syncthreads();
        sh[threadIdx.x] += add;
        __syncthreads();
    }
    if (i < N_L) {
        int excl = sh[threadIdx.x] - v + boff[blockIdx.x];
        rowptr[i] = excl;
        cursor[i] = excl;
    }
    if (i == 0) rowptr[N_L] = E_LL;
}

// ---- bucket fill: srcidx[pos] = row[e] via atomicExch (4B fabric) --------
__global__ void fill_kernel(const int* __restrict__ row,
                            const int* __restrict__ col,
                            int* __restrict__ cursor,
                            int* __restrict__ srcidx, int E) {
    int i = blockIdx.x * blockDim.x + threadIdx.x;
    int stride = gridDim.x * blockDim.x;
    for (; i < E; i += stride) {
        int c = col[i];
        int r = row[i];
        int pos = atomicAdd(&cursor[c], 1);
        atomicExch(&srcidx[pos], r);   // dword-granular memory-side store
    }
}

// ---- CSR gather: acc[c,:] = bf16( dinv[c] * sum_e xb[r_e,:] ) ------------
// one 64-lane wave per dst node; lane = feature channel (coalesced 128B rows)
__global__ __launch_bounds__(256) void gather_kernel(
    const unsigned short* __restrict__ xb, const int* __restrict__ rowptr,
    const int* __restrict__ srcidx, const float* __restrict__ dinv,
    unsigned short* __restrict__ acc) {
    int lane = threadIdx.x & 63;
    int c = (blockIdx.x * blockDim.x + threadIdx.x) >> 6;
    if (c >= N_L) return;

    int s = rowptr[c], e = rowptr[c + 1];
    int cnt = e - s;
    float a0 = 0.0f, a1 = 0.0f, a2 = 0.0f, a3 = 0.0f;
    int base = s;
    while (cnt > 0) {
        int take = (cnt < 64) ? cnt : 64;
        int src = (lane < take) ? srcidx[base + lane] : 0;
        int p = 0;
        for (; p + 4 <= take; p += 4) {
            int r0 = __shfl(src, p + 0);
            int r1 = __shfl(src, p + 1);
            int r2 = __shfl(src, p + 2);
            int r3 = __shfl(src, p + 3);
            a0 += bf2f(xb[(size_t)r0 * D_IN + lane]);
            a1 += bf2f(xb[(size_t)r1 * D_IN + lane]);
            a2 += bf2f(xb[(size_t)r2 * D_IN + lane]);
            a3 += bf2f(xb[(size_t)r3 * D_IN + lane]);
        }
        for (; p < take; ++p) {
            int r = __shfl(src, p);
            a0 += bf2f(xb[(size_t)r * D_IN + lane]);
        }
        base += take;
        cnt -= take;
    }
    float a = ((a0 + a1) + (a2 + a3)) * dinv[c];
    acc[(size_t)c * D_IN + lane] = f2bf(a);
}

// ---- out = relu(acc @ Wg + bg) @ Wl + bl  (acc is bf16) ------------------
__global__ __launch_bounds__(256) void epilogue_kernel(
    const unsigned short* __restrict__ acc,
    const float* __restrict__ Wg, const float* __restrict__ bg,
    const float* __restrict__ Wl, const float* __restrict__ bl,
    float* __restrict__ out, int n) {
    __shared__ float sWg[HCH][D_IN];
    __shared__ float sWl[HCH][D_OUT];
    __shared__ float sbg[HCH];
    __shared__ float sbl[D_OUT];
    for (int i = threadIdx.x; i < D_IN * HCH; i += blockDim.x)
        sWg[i >> 6][i & 63] = Wg[i];
    for (int i = threadIdx.x; i < HCH * D_OUT; i += blockDim.x)
        sWl[i >> 5][i & 31] = Wl[i];
    if (threadIdx.x < HCH)   sbg[threadIdx.x] = bg[threadIdx.x];
    if (threadIdx.x < D_OUT) sbl[threadIdx.x] = bl[threadIdx.x];
    __syncthreads();

    int i = blockIdx.x * blockDim.x + threadIdx.x;
    if (i >= n) return;

    const uint32* ap = (const uint32*)(acc + (size_t)i * D_IN);  // 32 uints

    float t[HCH];
    #pragma unroll
    for (int j = 0; j < HCH; ++j) t[j] = sbg[j];

    #pragma unroll
    for (int ku = 0; ku < D_IN / 2; ++ku) {
        uint32 u = ap[ku];
        float a0 = __uint_as_float(u << 16);
        float a1 = __uint_as_float(u & 0xffff0000u);
        int k0 = 2 * ku, k1 = 2 * ku + 1;
        const float4* w0 = (const float4*)&sWg[k0][0];
        const float4* w1 = (const float4*)&sWg[k1][0];
        #pragma unroll
        for (int j4 = 0; j4 < HCH / 4; ++j4) {
            float4 wa = w0[j4];
            float4 wb = w1[j4];
            t[4 * j4 + 0] += a0 * wa.x + a1 * wb.x;
            t[4 * j4 + 1] += a0 * wa.y + a1 * wb.y;
            t[4 * j4 + 2] += a0 * wa.z + a1 * wb.z;
            t[4 * j4 + 3] += a0 * wa.w + a1 * wb.w;
        }
    }
    #pragma unroll
    for (int j = 0; j < HCH; ++j) t[j] = fmaxf(t[j], 0.0f);

    float o[D_OUT];
    #pragma unroll
    for (int j = 0; j < D_OUT; ++j) o[j] = sbl[j];
    #pragma unroll
    for (int k = 0; k < HCH; ++k) {
        const float4* wr = (const float4*)&sWl[k][0];
        #pragma unroll
        for (int j4 = 0; j4 < D_OUT / 4; ++j4) {
            float4 w = wr[j4];
            o[4 * j4 + 0] += t[k] * w.x;
            o[4 * j4 + 1] += t[k] * w.y;
            o[4 * j4 + 2] += t[k] * w.z;
            o[4 * j4 + 3] += t[k] * w.w;
        }
    }

    float4* op = (float4*)(out + (size_t)i * D_OUT);
    #pragma unroll
    for (int j4 = 0; j4 < D_OUT / 4; ++j4)
        op[j4] = make_float4(o[4 * j4], o[4 * j4 + 1], o[4 * j4 + 2], o[4 * j4 + 3]);
}

extern "C" void kernel_launch(void* const* d_in, const int* in_sizes, int n_in,
                              void* d_out, int out_size, void* d_ws, size_t ws_size,
                              hipStream_t stream) {
    const float* x_local = (const float*)d_in[0];
    const float* W_gcn   = (const float*)d_in[2];
    const float* b_gcn   = (const float*)d_in[3];
    const float* W_lin   = (const float*)d_in[10];
    const float* b_lin   = (const float*)d_in[11];
    const int*   edge_ll = (const int*)d_in[12];
    const int*   row = edge_ll;           // edge_ll[0, :]
    const int*   col = edge_ll + E_LL;    // edge_ll[1, :]

    // workspace layout (~31.2 MB)
    int*   deg_i  = (int*)d_ws;                         // N_L
    int*   rowptr = deg_i + N_L;                        // N_L + 1
    int*   cursor = rowptr + N_L + 1;                   // N_L
    int*   bsum   = cursor + N_L;                       // 512
    int*   boff   = bsum + 512;                         // 512
    float* dinvp  = (float*)(boff + 512);               // N_L
    int*   srcidx = (int*)(dinvp + N_L);                // E_LL
    unsigned short* xb    = (unsigned short*)(srcidx + E_LL);   // N_L*64 bf16
    unsigned short* acc16 = xb + (size_t)N_L * D_IN;            // N_L*64 bf16
    float* out = (float*)d_out;

    hipMemsetAsync(deg_i, 0, (size_t)N_L * sizeof(int), stream);

    deg_kernel<<<1024, 256, 0, stream>>>(col, deg_i, E_LL);
    dinv_kernel<<<(N_L + 255) / 256, 256, 0, stream>>>(deg_i, dinvp, N_L);
    blocksum_kernel<<<NB, SCAN_BLK, 0, stream>>>(deg_i, bsum);
    scan_bsum_kernel<<<1, 512, 0, stream>>>(bsum, boff);
    block_scan_kernel<<<NB, SCAN_BLK, 0, stream>>>(deg_i, boff, rowptr, cursor);
    xbconv_kernel<<<2048, 256, 0, stream>>>(x_local, dinvp, xb);
    fill_kernel<<<1024, 256, 0, stream>>>(row, col, cursor, srcidx, E_LL);
    gather_kernel<<<(N_L * 64 + 255) / 256, 256, 0, stream>>>(
        xb, rowptr, srcidx, dinvp, acc16);
    epilogue_kernel<<<(N_L + 255) / 256, 256, 0, stream>>>(
        acc16, W_gcn, b_gcn, W_lin, b_lin, out, N_L);
}

// Round 4
// 236.345 us; speedup vs baseline: 1.1833x; 1.1833x over previous
//
#include <hip/hip_runtime.h>

#define N_L 100000
#define N_V 1000
#define D_IN 64
#define HCH 64
#define D_OUT 32
#define E_LL 1000000

#define SCAN_BLK 256
#define NB ((N_L + SCAN_BLK - 1) / SCAN_BLK)   // 391 blocks
#define NXCD 8
#define DST_PER_CLS (N_L / NXCD)               // 12500

typedef unsigned int uint32;

__device__ inline float bf2f(unsigned short u) {
    return __uint_as_float(((uint32)u) << 16);
}
__device__ inline unsigned short f2bf(float f) {   // round-to-nearest-even
    uint32 u = __float_as_uint(f);
    u = (u + 0x7fffu + ((u >> 16) & 1u)) >> 16;
    return (unsigned short)u;
}

// ---- deg_i[c] += 1 over all ll-edges (int atomics, 4B fabric each) ------
__global__ void deg_kernel(const int* __restrict__ col,
                           int* __restrict__ deg, int E) {
    int i = blockIdx.x * blockDim.x + threadIdx.x;
    int stride = gridDim.x * blockDim.x;
    for (; i < E; i += stride)
        atomicAdd(&deg[col[i]], 1);
}

// ---- dinv[i] = deg>0 ? rsqrt(deg) : 0 ------------------------------------
__global__ void dinv_kernel(const int* __restrict__ deg,
                            float* __restrict__ dinv, int n) {
    int i = blockIdx.x * blockDim.x + threadIdx.x;
    if (i < n) {
        int d = deg[i];
        dinv[i] = (d > 0) ? rsqrtf((float)d) : 0.0f;
    }
}

// ---- xb[r,:] = bf16(x[r,:] * dinv[r])  (streaming, float4 -> ushort4) ----
__global__ void xbconv_kernel(const float* __restrict__ x,
                              const float* __restrict__ dinv,
                              unsigned short* __restrict__ xb) {
    int n4 = N_L * D_IN / 4;
    int idx = blockIdx.x * blockDim.x + threadIdx.x;
    int stride = gridDim.x * blockDim.x;
    for (; idx < n4; idx += stride) {
        float4 v = ((const float4*)x)[idx];
        float d = dinv[idx >> 4];          // (idx*4)>>6
        ushort4 o;
        o.x = f2bf(v.x * d);
        o.y = f2bf(v.y * d);
        o.z = f2bf(v.z * d);
        o.w = f2bf(v.w * d);
        ((ushort4*)xb)[idx] = o;
    }
}

// ---- scan stage A: per-block sums ---------------------------------------
__global__ void blocksum_kernel(const int* __restrict__ deg,
                                int* __restrict__ bsum) {
    __shared__ int sh[SCAN_BLK];
    int i = blockIdx.x * SCAN_BLK + threadIdx.x;
    sh[threadIdx.x] = (i < N_L) ? deg[i] : 0;
    __syncthreads();
    for (int s = SCAN_BLK / 2; s > 0; s >>= 1) {
        if (threadIdx.x < s) sh[threadIdx.x] += sh[threadIdx.x + s];
        __syncthreads();
    }
    if (threadIdx.x == 0) bsum[blockIdx.x] = sh[0];
}

// ---- scan stage B: exclusive scan of block sums (single block) ----------
__global__ void scan_bsum_kernel(const int* __restrict__ bsum,
                                 int* __restrict__ boff) {
    __shared__ int sh[512];
    int v = (threadIdx.x < NB) ? bsum[threadIdx.x] : 0;
    sh[threadIdx.x] = v;
    __syncthreads();
    for (int ofs = 1; ofs < 512; ofs <<= 1) {
        int add = (threadIdx.x >= ofs) ? sh[threadIdx.x - ofs] : 0;
        __syncthreads();
        sh[threadIdx.x] += add;
        __syncthreads();
    }
    if (threadIdx.x < NB) boff[threadIdx.x] = sh[threadIdx.x] - v;  // exclusive
}

// ---- scan stage C: per-block exclusive scan + offset -> rowptr, cursor --
__global__ void block_scan_kernel(const int* __restrict__ deg,
                                  const int* __restrict__ boff,
                                  int* __restrict__ rowptr,
                                  int* __restrict__ cursor) {
    __shared__ int sh[SCAN_BLK];
    int i = blockIdx.x * SCAN_BLK + threadIdx.x;
    int v = (i < N_L) ? deg[i] : 0;
    sh[threadIdx.x] = v;
    __syncthreads();
    for (int ofs = 1; ofs < SCAN_BLK; ofs <<= 1) {
        int add = (threadIdx.x >= ofs) ? sh[threadIdx.x - ofs] : 0;
        __syncthreads();
        sh[threadIdx.x] += add;
        __syncthreads();
    }
    if (i < N_L) {
        int excl = sh[threadIdx.x] - v + boff[blockIdx.x];
        rowptr[i] = excl;
        cursor[i] = excl;
    }
    if (i == 0) rowptr[N_L] = E_LL;
}

// ---- bucket fill, XCD-partitioned by dst range ---------------------------
// class = bid & 7 maps to one XCD (empirical round-robin dispatch); each
// class owns a contiguous 512KB srcidx region -> lines stay in ONE L2,
// written back once (kills the ~16x writeback amplification).
__global__ void fill_kernel(const int* __restrict__ row,
                            const int* __restrict__ col,
                            int* __restrict__ cursor,
                            int* __restrict__ srcidx, int E) {
    int cls = blockIdx.x & (NXCD - 1);
    int lo = cls * DST_PER_CLS;
    int hi = lo + DST_PER_CLS;
    int i = (blockIdx.x >> 3) * blockDim.x + threadIdx.x;
    int stride = (gridDim.x >> 3) * blockDim.x;
    for (; i < E; i += stride) {
        int c = col[i];
        if (c < lo || c >= hi) continue;
        int pos = atomicAdd(&cursor[c], 1);
        srcidx[pos] = row[i];
    }
}

// ---- CSR gather: acc[c,:] = bf16( dinv[c] * sum_e xb[r_e,:] ) ------------
__global__ __launch_bounds__(256) void gather_kernel(
    const unsigned short* __restrict__ xb, const int* __restrict__ rowptr,
    const int* __restrict__ srcidx, const float* __restrict__ dinv,
    unsigned short* __restrict__ acc) {
    int lane = threadIdx.x & 63;
    int c = (blockIdx.x * blockDim.x + threadIdx.x) >> 6;
    if (c >= N_L) return;

    int s = rowptr[c], e = rowptr[c + 1];
    int cnt = e - s;
    float a0 = 0.0f, a1 = 0.0f, a2 = 0.0f, a3 = 0.0f;
    int base = s;
    while (cnt > 0) {
        int take = (cnt < 64) ? cnt : 64;
        int src = (lane < take) ? srcidx[base + lane] : 0;
        int p = 0;
        for (; p + 4 <= take; p += 4) {
            int r0 = __shfl(src, p + 0);
            int r1 = __shfl(src, p + 1);
            int r2 = __shfl(src, p + 2);
            int r3 = __shfl(src, p + 3);
            a0 += bf2f(xb[(size_t)r0 * D_IN + lane]);
            a1 += bf2f(xb[(size_t)r1 * D_IN + lane]);
            a2 += bf2f(xb[(size_t)r2 * D_IN + lane]);
            a3 += bf2f(xb[(size_t)r3 * D_IN + lane]);
        }
        for (; p < take; ++p) {
            int r = __shfl(src, p);
            a0 += bf2f(xb[(size_t)r * D_IN + lane]);
        }
        base += take;
        cnt -= take;
    }
    float a = ((a0 + a1) + (a2 + a3)) * dinv[c];
    acc[(size_t)c * D_IN + lane] = f2bf(a);
}

// ---- out = relu(acc @ Wg + bg) @ Wl + bl  (acc is bf16) ------------------
__global__ __launch_bounds__(256) void epilogue_kernel(
    const unsigned short* __restrict__ acc,
    const float* __restrict__ Wg, const float* __restrict__ bg,
    const float* __restrict__ Wl, const float* __restrict__ bl,
    float* __restrict__ out, int n) {
    __shared__ float sWg[HCH][D_IN];
    __shared__ float sWl[HCH][D_OUT];
    __shared__ float sbg[HCH];
    __shared__ float sbl[D_OUT];
    for (int i = threadIdx.x; i < D_IN * HCH; i += blockDim.x)
        sWg[i >> 6][i & 63] = Wg[i];
    for (int i = threadIdx.x; i < HCH * D_OUT; i += blockDim.x)
        sWl[i >> 5][i & 31] = Wl[i];
    if (threadIdx.x < HCH)   sbg[threadIdx.x] = bg[threadIdx.x];
    if (threadIdx.x < D_OUT) sbl[threadIdx.x] = bl[threadIdx.x];
    __syncthreads();

    int i = blockIdx.x * blockDim.x + threadIdx.x;
    if (i >= n) return;

    const uint32* ap = (const uint32*)(acc + (size_t)i * D_IN);  // 32 uints

    float t[HCH];
    #pragma unroll
    for (int j = 0; j < HCH; ++j) t[j] = sbg[j];

    #pragma unroll
    for (int ku = 0; ku < D_IN / 2; ++ku) {
        uint32 u = ap[ku];
        float a0 = __uint_as_float(u << 16);
        float a1 = __uint_as_float(u & 0xffff0000u);
        int k0 = 2 * ku, k1 = 2 * ku + 1;
        const float4* w0 = (const float4*)&sWg[k0][0];
        const float4* w1 = (const float4*)&sWg[k1][0];
        #pragma unroll
        for (int j4 = 0; j4 < HCH / 4; ++j4) {
            float4 wa = w0[j4];
            float4 wb = w1[j4];
            t[4 * j4 + 0] += a0 * wa.x + a1 * wb.x;
            t[4 * j4 + 1] += a0 * wa.y + a1 * wb.y;
            t[4 * j4 + 2] += a0 * wa.z + a1 * wb.z;
            t[4 * j4 + 3] += a0 * wa.w + a1 * wb.w;
        }
    }
    #pragma unroll
    for (int j = 0; j < HCH; ++j) t[j] = fmaxf(t[j], 0.0f);

    float o[D_OUT];
    #pragma unroll
    for (int j = 0; j < D_OUT; ++j) o[j] = sbl[j];
    #pragma unroll
    for (int k = 0; k < HCH; ++k) {
        const float4* wr = (const float4*)&sWl[k][0];
        #pragma unroll
        for (int j4 = 0; j4 < D_OUT / 4; ++j4) {
            float4 w = wr[j4];
            o[4 * j4 + 0] += t[k] * w.x;
            o[4 * j4 + 1] += t[k] * w.y;
            o[4 * j4 + 2] += t[k] * w.z;
            o[4 * j4 + 3] += t[k] * w.w;
        }
    }

    float4* op = (float4*)(out + (size_t)i * D_OUT);
    #pragma unroll
    for (int j4 = 0; j4 < D_OUT / 4; ++j4)
        op[j4] = make_float4(o[4 * j4], o[4 * j4 + 1], o[4 * j4 + 2], o[4 * j4 + 3]);
}

extern "C" void kernel_launch(void* const* d_in, const int* in_sizes, int n_in,
                              void* d_out, int out_size, void* d_ws, size_t ws_size,
                              hipStream_t stream) {
    const float* x_local = (const float*)d_in[0];
    const float* W_gcn   = (const float*)d_in[2];
    const float* b_gcn   = (const float*)d_in[3];
    const float* W_lin   = (const float*)d_in[10];
    const float* b_lin   = (const float*)d_in[11];
    const int*   edge_ll = (const int*)d_in[12];
    const int*   row = edge_ll;           // edge_ll[0, :]
    const int*   col = edge_ll + E_LL;    // edge_ll[1, :]

    // workspace layout (~31.2 MB)
    int*   deg_i  = (int*)d_ws;                         // N_L
    int*   rowptr = deg_i + N_L;                        // N_L + 1
    int*   cursor = rowptr + N_L + 1;                   // N_L
    int*   bsum   = cursor + N_L;                       // 512
    int*   boff   = bsum + 512;                         // 512
    float* dinvp  = (float*)(boff + 512);               // N_L
    int*   srcidx = (int*)(dinvp + N_L);                // E_LL
    unsigned short* xb    = (unsigned short*)(srcidx + E_LL);   // N_L*64 bf16
    unsigned short* acc16 = xb + (size_t)N_L * D_IN;            // N_L*64 bf16
    float* out = (float*)d_out;

    hipMemsetAsync(deg_i, 0, (size_t)N_L * sizeof(int), stream);

    deg_kernel<<<1024, 256, 0, stream>>>(col, deg_i, E_LL);
    dinv_kernel<<<(N_L + 255) / 256, 256, 0, stream>>>(deg_i, dinvp, N_L);
    blocksum_kernel<<<NB, SCAN_BLK, 0, stream>>>(deg_i, bsum);
    scan_bsum_kernel<<<1, 512, 0, stream>>>(bsum, boff);
    block_scan_kernel<<<NB, SCAN_BLK, 0, stream>>>(deg_i, boff, rowptr, cursor);
    xbconv_kernel<<<2048, 256, 0, stream>>>(x_local, dinvp, xb);
    fill_kernel<<<1024, 256, 0, stream>>>(row, col, cursor, srcidx, E_LL);
    gather_kernel<<<(N_L * 64 + 255) / 256, 256, 0, stream>>>(
        xb, rowptr, srcidx, dinvp, acc16);
    epilogue_kernel<<<(N_L + 255) / 256, 256, 0, stream>>>(
        acc16, W_gcn, b_gcn, W_lin, b_lin, out, N_L);
}

// Round 5
// 166.201 us; speedup vs baseline: 1.6827x; 1.4220x over previous
//
#include <hip/hip_runtime.h>

#define N_L 100000
#define N_V 1000
#define D_IN 64
#define HCH 64
#define D_OUT 32
#define E_LL 1000000

#define SCAN_BLK 256
#define NB ((N_L + SCAN_BLK - 1) / SCAN_BLK)   // 391 blocks
#define NXCD 8
#define DST_PER_CLS (N_L / NXCD)               // 12500

typedef unsigned int uint32;
typedef __attribute__((ext_vector_type(8))) short bfx8;   // 8 bf16 (4 VGPR)
typedef __attribute__((ext_vector_type(4))) float f32x4;  // MFMA C/D frag

__device__ inline float bf2f(unsigned short u) {
    return __uint_as_float(((uint32)u) << 16);
}
__device__ inline unsigned short f2bf(float f) {   // round-to-nearest-even
    uint32 u = __float_as_uint(f);
    u = (u + 0x7fffu + ((u >> 16) & 1u)) >> 16;
    return (unsigned short)u;
}

// ---- deg_i[c] += 1 over all ll-edges (int atomics, 4B fabric each) ------
__global__ void deg_kernel(const int* __restrict__ col,
                           int* __restrict__ deg, int E) {
    int i = blockIdx.x * blockDim.x + threadIdx.x;
    int stride = gridDim.x * blockDim.x;
    for (; i < E; i += stride)
        atomicAdd(&deg[col[i]], 1);
}

// ---- dinv[i] = deg>0 ? rsqrt(deg) : 0 ------------------------------------
__global__ void dinv_kernel(const int* __restrict__ deg,
                            float* __restrict__ dinv, int n) {
    int i = blockIdx.x * blockDim.x + threadIdx.x;
    if (i < n) {
        int d = deg[i];
        dinv[i] = (d > 0) ? rsqrtf((float)d) : 0.0f;
    }
}

// ---- xb[r,:] = bf16(x[r,:] * dinv[r])  (streaming, float4 -> ushort4) ----
__global__ void xbconv_kernel(const float* __restrict__ x,
                              const float* __restrict__ dinv,
                              unsigned short* __restrict__ xb) {
    int n4 = N_L * D_IN / 4;
    int idx = blockIdx.x * blockDim.x + threadIdx.x;
    int stride = gridDim.x * blockDim.x;
    for (; idx < n4; idx += stride) {
        float4 v = ((const float4*)x)[idx];
        float d = dinv[idx >> 4];          // (idx*4)>>6
        ushort4 o;
        o.x = f2bf(v.x * d);
        o.y = f2bf(v.y * d);
        o.z = f2bf(v.z * d);
        o.w = f2bf(v.w * d);
        ((ushort4*)xb)[idx] = o;
    }
}

// ---- scan stage A: per-block sums ---------------------------------------
__global__ void blocksum_kernel(const int* __restrict__ deg,
                                int* __restrict__ bsum) {
    __shared__ int sh[SCAN_BLK];
    int i = blockIdx.x * SCAN_BLK + threadIdx.x;
    sh[threadIdx.x] = (i < N_L) ? deg[i] : 0;
    __syncthreads();
    for (int s = SCAN_BLK / 2; s > 0; s >>= 1) {
        if (threadIdx.x < s) sh[threadIdx.x] += sh[threadIdx.x + s];
        __syncthreads();
    }
    if (threadIdx.x == 0) bsum[blockIdx.x] = sh[0];
}

// ---- scan stage B: exclusive scan of block sums (single block) ----------
__global__ void scan_bsum_kernel(const int* __restrict__ bsum,
                                 int* __restrict__ boff) {
    __shared__ int sh[512];
    int v = (threadIdx.x < NB) ? bsum[threadIdx.x] : 0;
    sh[threadIdx.x] = v;
    __syncthreads();
    for (int ofs = 1; ofs < 512; ofs <<= 1) {
        int add = (threadIdx.x >= ofs) ? sh[threadIdx.x - ofs] : 0;
        __syncthreads();
        sh[threadIdx.x] += add;
        __syncthreads();
    }
    if (threadIdx.x < NB) boff[threadIdx.x] = sh[threadIdx.x] - v;  // exclusive
}

// ---- scan stage C: per-block exclusive scan + offset -> rowptr, cursor --
__global__ void block_scan_kernel(const int* __restrict__ deg,
                                  const int* __restrict__ boff,
                                  int* __restrict__ rowptr,
                                  int* __restrict__ cursor) {
    __shared__ int sh[SCAN_BLK];
    int i = blockIdx.x * SCAN_BLK + threadIdx.x;
    int v = (i < N_L) ? deg[i] : 0;
    sh[threadIdx.x] = v;
    __syncthreads();
    for (int ofs = 1; ofs < SCAN_BLK; ofs <<= 1) {
        int add = (threadIdx.x >= ofs) ? sh[threadIdx.x - ofs] : 0;
        __syncthreads();
        sh[threadIdx.x] += add;
        __syncthreads();
    }
    if (i < N_L) {
        int excl = sh[threadIdx.x] - v + boff[blockIdx.x];
        rowptr[i] = excl;
        cursor[i] = excl;
    }
    if (i == 0) rowptr[N_L] = E_LL;
}

// ---- bucket fill, XCD-partitioned by dst range ---------------------------
__global__ void fill_kernel(const int* __restrict__ row,
                            const int* __restrict__ col,
                            int* __restrict__ cursor,
                            int* __restrict__ srcidx, int E) {
    int cls = blockIdx.x & (NXCD - 1);
    int lo = cls * DST_PER_CLS;
    int hi = lo + DST_PER_CLS;
    int i = (blockIdx.x >> 3) * blockDim.x + threadIdx.x;
    int stride = (gridDim.x >> 3) * blockDim.x;
    for (; i < E; i += stride) {
        int c = col[i];
        if (c < lo || c >= hi) continue;
        int pos = atomicAdd(&cursor[c], 1);
        srcidx[pos] = row[i];
    }
}

// ---- CSR gather: acc[c,:] = bf16( dinv[c] * sum_e xb[r_e,:] ) ------------
__global__ __launch_bounds__(256) void gather_kernel(
    const unsigned short* __restrict__ xb, const int* __restrict__ rowptr,
    const int* __restrict__ srcidx, const float* __restrict__ dinv,
    unsigned short* __restrict__ acc) {
    int lane = threadIdx.x & 63;
    int c = (blockIdx.x * blockDim.x + threadIdx.x) >> 6;
    if (c >= N_L) return;

    int s = rowptr[c], e = rowptr[c + 1];
    int cnt = e - s;
    float a0 = 0.0f, a1 = 0.0f, a2 = 0.0f, a3 = 0.0f;
    int base = s;
    while (cnt > 0) {
        int take = (cnt < 64) ? cnt : 64;
        int src = (lane < take) ? srcidx[base + lane] : 0;
        int p = 0;
        for (; p + 4 <= take; p += 4) {
            int r0 = __shfl(src, p + 0);
            int r1 = __shfl(src, p + 1);
            int r2 = __shfl(src, p + 2);
            int r3 = __shfl(src, p + 3);
            a0 += bf2f(xb[(size_t)r0 * D_IN + lane]);
            a1 += bf2f(xb[(size_t)r1 * D_IN + lane]);
            a2 += bf2f(xb[(size_t)r2 * D_IN + lane]);
            a3 += bf2f(xb[(size_t)r3 * D_IN + lane]);
        }
        for (; p < take; ++p) {
            int r = __shfl(src, p);
            a0 += bf2f(xb[(size_t)r * D_IN + lane]);
        }
        base += take;
        cnt -= take;
    }
    float a = ((a0 + a1) + (a2 + a3)) * dinv[c];
    acc[(size_t)c * D_IN + lane] = f2bf(a);
}

// ---- MFMA epilogue: out = relu(acc @ Wg + bg) @ Wl + bl ------------------
// One wave per 16 nodes; mfma_f32_16x16x32_bf16.
// A-frag: lane holds A[lane&15][(lane>>4)*8 + j]  (8 contiguous k, 16B load)
// B-frag: lane holds B[(lane>>4)*8 + j][lane&15]
// C/D   : lane, reg i -> D[(lane>>4)*4 + i][lane&15]   [m89-verified]
__global__ __launch_bounds__(640) void epi_mfma_kernel(
    const unsigned short* __restrict__ acc,
    const float* __restrict__ Wg, const float* __restrict__ bg,
    const float* __restrict__ Wl, const float* __restrict__ bl,
    float* __restrict__ out)
{
    __shared__ __align__(16) unsigned short hbuf[10][16][72];  // +pad: 2-way-free banks
    const int w    = threadIdx.x >> 6;
    const int lane = threadIdx.x & 63;
    const int lm   = lane & 15;
    const int lg   = lane >> 4;
    const int kseg = lg * 8;

    const int wtile = blockIdx.x * 10 + w;     // 0..6249 (exact, no tail)
    const int m0 = wtile * 16;

    // A fragments from acc rows (bf16, 16B aligned)
    const unsigned short* arow = acc + (size_t)(m0 + lm) * D_IN + kseg;
    bfx8 a0 = *(const bfx8*)(arow);
    bfx8 a1 = *(const bfx8*)(arow + 32);

    // GEMM1: c[n] over 4 N-tiles, K = 2 steps; B-frags built from f32 Wg[k][j]
    f32x4 c[4];
    #pragma unroll
    for (int n = 0; n < 4; ++n) {
        bfx8 b0, b1;
        #pragma unroll
        for (int jj = 0; jj < 8; ++jj) {
            b0[jj] = (short)f2bf(Wg[(kseg + jj) * HCH      + n * 16 + lm]);
            b1[jj] = (short)f2bf(Wg[(32 + kseg + jj) * HCH + n * 16 + lm]);
        }
        f32x4 t = {0.0f, 0.0f, 0.0f, 0.0f};
        t = __builtin_amdgcn_mfma_f32_16x16x32_bf16(a0, b0, t, 0, 0, 0);
        t = __builtin_amdgcn_mfma_f32_16x16x32_bf16(a1, b1, t, 0, 0, 0);
        c[n] = t;
    }

    // bias + relu + bf16, transpose via per-wave LDS tile
    #pragma unroll
    for (int n = 0; n < 4; ++n) {
        float bgv = bg[n * 16 + lm];
        #pragma unroll
        for (int i = 0; i < 4; ++i) {
            float h = fmaxf(c[n][i] + bgv, 0.0f);
            hbuf[w][lg * 4 + i][n * 16 + lm] = f2bf(h);
        }
    }
    __syncthreads();

    bfx8 a20 = *(const bfx8*)(&hbuf[w][lm][kseg]);
    bfx8 a21 = *(const bfx8*)(&hbuf[w][lm][32 + kseg]);

    // GEMM2: 2 N-tiles, K = 2 steps; B-frags from f32 Wl[k][j]
    #pragma unroll
    for (int n2 = 0; n2 < 2; ++n2) {
        bfx8 b0, b1;
        #pragma unroll
        for (int jj = 0; jj < 8; ++jj) {
            b0[jj] = (short)f2bf(Wl[(kseg + jj) * D_OUT      + n2 * 16 + lm]);
            b1[jj] = (short)f2bf(Wl[(32 + kseg + jj) * D_OUT + n2 * 16 + lm]);
        }
        f32x4 d = {0.0f, 0.0f, 0.0f, 0.0f};
        d = __builtin_amdgcn_mfma_f32_16x16x32_bf16(a20, b0, d, 0, 0, 0);
        d = __builtin_amdgcn_mfma_f32_16x16x32_bf16(a21, b1, d, 0, 0, 0);
        float blv = bl[n2 * 16 + lm];
        #pragma unroll
        for (int i = 0; i < 4; ++i)
            out[(size_t)(m0 + lg * 4 + i) * D_OUT + n2 * 16 + lm] = d[i] + blv;
    }
}

extern "C" void kernel_launch(void* const* d_in, const int* in_sizes, int n_in,
                              void* d_out, int out_size, void* d_ws, size_t ws_size,
                              hipStream_t stream) {
    const float* x_local = (const float*)d_in[0];
    const float* W_gcn   = (const float*)d_in[2];
    const float* b_gcn   = (const float*)d_in[3];
    const float* W_lin   = (const float*)d_in[10];
    const float* b_lin   = (const float*)d_in[11];
    const int*   edge_ll = (const int*)d_in[12];
    const int*   row = edge_ll;           // edge_ll[0, :]
    const int*   col = edge_ll + E_LL;    // edge_ll[1, :]

    // workspace layout, 256B-aligned offsets (total ~31.21 MB)
    char* base = (char*)d_ws;
    int*   deg_i  = (int*)(base + 0);                 // 400000 B
    int*   rowptr = (int*)(base + 400128);            // 400004 B
    int*   cursor = (int*)(base + 800256);            // 400000 B
    int*   bsum   = (int*)(base + 1200384);           // 2048 B
    int*   boff   = (int*)(base + 1202432);           // 2048 B
    float* dinvp  = (float*)(base + 1204480);         // 400000 B
    int*   srcidx = (int*)(base + 1604480);           // 4000000 B
    unsigned short* xb    = (unsigned short*)(base + 5604480);   // 12.8 MB (16B aligned)
    unsigned short* acc16 = (unsigned short*)(base + 18404480);  // 12.8 MB (16B aligned)
    float* out = (float*)d_out;

    hipMemsetAsync(deg_i, 0, (size_t)N_L * sizeof(int), stream);

    deg_kernel<<<1024, 256, 0, stream>>>(col, deg_i, E_LL);
    dinv_kernel<<<(N_L + 255) / 256, 256, 0, stream>>>(deg_i, dinvp, N_L);
    blocksum_kernel<<<NB, SCAN_BLK, 0, stream>>>(deg_i, bsum);
    scan_bsum_kernel<<<1, 512, 0, stream>>>(bsum, boff);
    block_scan_kernel<<<NB, SCAN_BLK, 0, stream>>>(deg_i, boff, rowptr, cursor);
    xbconv_kernel<<<2048, 256, 0, stream>>>(x_local, dinvp, xb);
    fill_kernel<<<1024, 256, 0, stream>>>(row, col, cursor, srcidx, E_LL);
    gather_kernel<<<(N_L * 64 + 255) / 256, 256, 0, stream>>>(
        xb, rowptr, srcidx, dinvp, acc16);
    epi_mfma_kernel<<<625, 640, 0, stream>>>(
        acc16, W_gcn, b_gcn, W_lin, b_lin, out);
}